// Round 13
// baseline (1020.553 us; speedup 1.0000x reference)
//
#include <hip/hip_runtime.h>

#define D_IN 2312
#define HID  800
#define NCLS 10
#define BATCH 128
#define TSTEPS 300
#define WIN  50

#define MT 128                             // block tile rows (2 waves x 64)
#define NT 32
#define BKK 8                              // 2312 = 289*8 EXACT -> no tail guards
#define NSLAB 289
#define NTM 50                             // 6400/128
#define NTN 25                             // 800/32, exact
#define GEMM_BLOCKS (NTM * NTN)            // 1250 two-wave tiles
#define BLK 128
#define RPASTE 1920                        // paste blocks appended to recur launch
#define TOTQ (BATCH * D_IN * (TSTEPS / 4)) // 22,195,200 float4s of X

// ---------------------------------------------------------------------------
// GEMM kernel — 8x4-per-thread micro-kernel, BKK=8.
// Why this works where R2/R10 failed: their spills came from STAGING register
// pressure (R2: aN[16]+bN[4]=20 live; R10: +20 for dbuf). BKK=8 needs only
// aN[8]+bN[2]=10 live staging regs (LESS than the proven 48-VGPR kernel's 12)
// while doubling per-thread FMA work: 3 ds_read_b128 per 32 FMAs (was 2/16,
// -25% LDS traffic/FMA) and halving non-FMA VALU per FMA. 2312%8==0 kills
// the partial-slab branch entirely. Same barrier cadence (one pair per 256
// per-thread FMAs). Plain __launch_bounds__(128) (R2's ",4" implicated in
// its spill). XCD swizzle for 1250 = 8*156+2 (mechanism proven R10/R11:
// FETCH 500->181 MB). All 1250 blocks co-resident -> no dispatch tail.
// Per-output k-accumulation strictly sequential fmaf, k ascending ->
// bit-identical P.
// ---------------------------------------------------------------------------
__global__ __launch_bounds__(BLK) void gemm_kernel(
    const float* __restrict__ inp,   // [B][D_IN][WIN]
    const float* __restrict__ W1,    // [HID][D_IN]
    float*       __restrict__ P)     // [6400][HID]
{
  __shared__ float As[BKK][MT];       // 4 KB
  __shared__ float Bs[BKK][NT + 4];   // 1.125 KB

  int t   = threadIdx.x;
  int bx0 = blockIdx.x;

  // bijective XCD swizzle: 1250 = 8*156 + 2
  int xcd = bx0 & 7;
  int jj  = bx0 >> 3;
  const int q8 = GEMM_BLOCKS >> 3;      // 156
  const int r8 = GEMM_BLOCKS & 7;       // 2
  int bx = (xcd < r8 ? xcd * (q8 + 1) : r8 * (q8 + 1) + (xcd - r8) * q8) + jj;

  int mt = bx / NTN;                 // consecutive logical blocks share m-tile
  int nt = bx - mt * NTN;
  int m0 = mt * MT, n0 = nt * NT;

  // A staging: one row per thread, 8 k's (stride WIN floats)
  int am = t;                        // 0..127
  int r  = m0 + am;
  int bb = r / 50, ss = r - bb * 50;
  const float* aptr = inp + (size_t)bb * (D_IN * WIN) + ss;   // + k*WIN

  // B staging: 32 n x 8 k by 128 threads (2 each), coalesced along k
  int bn = t >> 3;                   // 0..15
  int bk = t & 7;                    // 0..7

  int ah = t >> 6;                   // wave id
  int l  = t & 63;
  int lm = l & 7;                    // m micro-group (8 rows each)
  int ln = l >> 3;                   // n micro-group (4 cols each)
  int tm = ah * 64 + lm * 8;         // wave ah owns rows [ah*64, ah*64+64)
  int tn = ln * 4;

  float aN[8], bN[2];
#pragma unroll
  for (int q = 0; q < 8; ++q) aN[q] = aptr[q * WIN];
#pragma unroll
  for (int p = 0; p < 2; ++p)
    bN[p] = W1[(size_t)(n0 + bn + 16 * p) * D_IN + bk];

  float acc[8][4] = {};

  for (int k0 = 0; k0 < D_IN; k0 += BKK) {   // 289 slabs, ALL full
#pragma unroll
    for (int q = 0; q < 8; ++q) As[q][am] = aN[q];
#pragma unroll
    for (int p = 0; p < 2; ++p) Bs[bk][bn + 16 * p] = bN[p];
    __syncthreads();

    int kn0 = k0 + BKK;
    if (kn0 < D_IN) {
      // guard-free prefetch: every slab is full (2312 % 8 == 0)
#pragma unroll
      for (int q = 0; q < 8; ++q) aN[q] = aptr[(kn0 + q) * WIN];
#pragma unroll
      for (int p = 0; p < 2; ++p)
        bN[p] = W1[(size_t)(n0 + bn + 16 * p) * D_IN + kn0 + bk];
    }

#pragma unroll
    for (int kk = 0; kk < BKK; ++kk) {
      float4 A0 = *(const float4*)&As[kk][tm];
      float4 A1 = *(const float4*)&As[kk][tm + 4];
      float4 B0 = *(const float4*)&Bs[kk][tn];
      float av[8] = {A0.x, A0.y, A0.z, A0.w, A1.x, A1.y, A1.z, A1.w};
      float bv[4] = {B0.x, B0.y, B0.z, B0.w};
#pragma unroll
      for (int i = 0; i < 8; ++i)
#pragma unroll
        for (int j = 0; j < 4; ++j)
          acc[i][j] += av[i] * bv[j];
    }
    __syncthreads();
  }

#pragma unroll
  for (int i = 0; i < 8; ++i) {
    int row = m0 + tm + i;
    *(float4*)&P[(size_t)row * HID + n0 + tn] =
        make_float4(acc[i][0], acc[i][1], acc[i][2], acc[i][3]);
  }
}

// ---------------------------------------------------------------------------
// DPP full-wave sum (proven round 6): VALU-speed cross-lane, no LDS pipe.
// ---------------------------------------------------------------------------
template <int CTRL>
__device__ __forceinline__ float dpp_add(float s) {
  return s + __int_as_float(__builtin_amdgcn_update_dpp(
      0, __float_as_int(s), CTRL, 0xf, 0xf, true));
}
__device__ __forceinline__ float wave_sum(float s) {
  s = dpp_add<0x111>(s);   // row_shr:1
  s = dpp_add<0x112>(s);   // row_shr:2
  s = dpp_add<0x114>(s);   // row_shr:4
  s = dpp_add<0x118>(s);   // row_shr:8   -> lane15 of each row = row sum
  s = dpp_add<0x142>(s);   // row_bcast:15 -> lane31 = r0+r1, lane63 = r2+r3
  s = dpp_add<0x143>(s);   // row_bcast:31 -> lane63 = total
  return __int_as_float(__builtin_amdgcn_readlane(__float_as_int(s), 63));
}

// ---------------------------------------------------------------------------
// Recurrence v7 — EXACT R12 version (best measured). W2/Wc/b1 in registers,
// DPP reductions, 1-step P prefetch; paste rides as blocks >= BATCH (proven
// ~free under the latency-bound recurrence).
// ---------------------------------------------------------------------------
__global__ __launch_bounds__(64, 1) void recur_kernel(
    const float* __restrict__ P,    // [6400][HID]
    const float* __restrict__ W2,   // [NCLS][HID]
    const float* __restrict__ b2,   // [NCLS]
    const float* __restrict__ Wc,   // [HID+4]
    const float* __restrict__ bc,   // [1]
    const float* __restrict__ b1,   // [HID]
    const int*   __restrict__ idx,  // [B]
    float*       __restrict__ out,  // [B][NCLS]
    const float* __restrict__ inp,  // [B][D_IN][WIN]  (paste)
    float*       __restrict__ outX) // [B][D_IN][T]    (paste)
{
  int L = threadIdx.x;
  int b = blockIdx.x;

  if (b >= BATCH) {
    // ---- paste path: X = zeros with input window pasted at idx[b] ----
    int tid = (b - BATCH) * 64 + L;
    const int stride = RPASTE * 64;
    for (int i = tid; i < TOTQ; i += stride) {
      int q  = i % 75;
      int rd = i / 75;
      int bb = rd / D_IN;
      int d  = rd - bb * D_IN;
      int ib = idx[bb];
      const float* ip = inp + (size_t)bb * (D_IN * WIN) + (size_t)d * WIN;
      int t0 = q * 4;
      float v[4];
#pragma unroll
      for (int e = 0; e < 4; ++e) {
        unsigned w = (unsigned)(t0 + e - ib);
        v[e] = (w < (unsigned)WIN) ? ip[w] : 0.f;
      }
      *(float4*)&outX[(size_t)rd * TSTEPS + t0] = make_float4(v[0], v[1], v[2], v[3]);
    }
    return;
  }

  int myidx = idx[b];
  const float* Pb = P + (size_t)b * WIN * HID;

  float m[13], b1r[13], wcr[13];
  float w2r[NCLS][13];
  unsigned smask = 0;
#pragma unroll
  for (int rr = 0; rr < 13; ++rr) {
    int j = L + 64 * rr;
    bool ok = (j < HID);
    m[rr]   = 0.f;
    b1r[rr] = ok ? b1[j] : 0.f;
    wcr[rr] = ok ? Wc[j] : 0.f;
#pragma unroll
    for (int c = 0; c < NCLS; ++c)
      w2r[c][rr] = ok ? W2[c * HID + j] : 0.f;
  }

  float cm = 0.f, cs = 0.f, bgt = 1.f;
  float bc0 = bc[0];
  float wf0 = Wc[HID], wf1 = Wc[HID + 1], wf2 = Wc[HID + 2], wf3 = Wc[HID + 3];

  float h2m[10], h2s[10], sum2[10], b2r[10];
#pragma unroll
  for (int c = 0; c < NCLS; ++c) { h2m[c] = 0.f; h2s[c] = 0.f; sum2[c] = 0.f; b2r[c] = b2[c]; }

  // prefetch P row for step 0
  float cur[13];
  {
    unsigned w0 = (unsigned)(0 - myidx);
    if (w0 < (unsigned)WIN) {
      const float* Pr = Pb + (size_t)w0 * HID;
#pragma unroll
      for (int rr = 0; rr < 13; ++rr) {
        int j = L + 64 * rr;
        cur[rr] = (j < HID) ? Pr[j] : 0.f;
      }
    } else {
#pragma unroll
      for (int rr = 0; rr < 13; ++rr) cur[rr] = 0.f;
    }
  }

  for (int step = 0; step < TSTEPS; ++step) {
    float gate = (step == 0) ? 1.f : cs;

    // unconditional prefetch of next step's P row (independent of this
    // step's chain; gating is applied at use as *gate, exact for {0,1})
    float nxt[13];
    {
      unsigned wn = (unsigned)(step + 1 - myidx);
      if (wn < (unsigned)WIN) {
        const float* Pr = Pb + (size_t)wn * HID;
#pragma unroll
        for (int rr = 0; rr < 13; ++rr) {
          int j = L + 64 * rr;
          nxt[rr] = (j < HID) ? Pr[j] : 0.f;
        }
      } else {
#pragma unroll
        for (int rr = 0; rr < 13; ++rr) nxt[rr] = 0.f;
      }
    }

    unsigned nmask = 0;
#pragma unroll
    for (int rr = 0; rr < 13; ++rr) {
      float mprev = ((smask >> rr) & 1u) ? 0.f : m[rr] * 0.1f;
      float mv = mprev + cur[rr] * gate + b1r[rr];
      m[rr] = mv;
      nmask |= (mv > 0.5f) ? (1u << rr) : 0u;
    }
    smask = nmask;

    unsigned long long ball = __ballot(smask != 0u);

    float ctrl = 0.f;
    float dot[10];
#pragma unroll
    for (int c = 0; c < NCLS; ++c) dot[c] = 0.f;

    if (ball) {
      // ctrl dot: branchless FMA over own units, DPP wave reduce
      float cacc = 0.f;
#pragma unroll
      for (int rr = 0; rr < 13; ++rr) {
        float f = (float)((smask >> rr) & 1u);
        cacc = fmaf(f, wcr[rr], cacc);
      }
      ctrl = wave_sum(cacc);

      // h2 dots: per-lane partials over own 13 units (all-register), then
      // DPP wave reduce x10
#pragma unroll
      for (int rr = 0; rr < 13; ++rr) {
        float f = (float)((smask >> rr) & 1u);
#pragma unroll
        for (int c = 0; c < NCLS; ++c)
          dot[c] = fmaf(f, w2r[c][rr], dot[c]);
      }
#pragma unroll
      for (int c = 0; c < NCLS; ++c) dot[c] = wave_sum(dot[c]);
    }

    // ctrl neuron + budget (uses prev-step cs, then updates it)
    bgt += (cs == 1.f) ? 1.f : 0.f;
    float fq = wf0;
    if ((step & 1) == 0)   fq += wf1;
    if (step % 10 == 0)    fq += wf2;
    if (step % 100 == 0)   fq += wf3;
    float cv = (cs != 0.f ? 0.f : cm * 0.1f) + ctrl + fq + bc0;
    cm = cv;
    cs = (cv > 0.5f) ? 1.f : 0.f;

    // h2 membrane update every step (dot==0 on silent steps)
#pragma unroll
    for (int c = 0; c < NCLS; ++c) {
      float v = (h2s[c] != 0.f ? 0.f : h2m[c] * 0.1f) + dot[c] + b2r[c];
      h2m[c] = v;
      h2s[c] = (v > 0.5f) ? 1.f : 0.f;
      sum2[c] += h2s[c];
    }

#pragma unroll
    for (int rr = 0; rr < 13; ++rr) cur[rr] = nxt[rr];
  }

  if (L == 0) {
#pragma unroll
    for (int c = 0; c < NCLS; ++c) out[b * NCLS + c] = sum2[c] / bgt;
  }
}

// ---------------------------------------------------------------------------
extern "C" void kernel_launch(void* const* d_in, const int* in_sizes, int n_in,
                              void* d_out, int out_size, void* d_ws, size_t ws_size,
                              hipStream_t stream) {
  const float* inp = (const float*)d_in[0];
  const int*   idx = (const int*)d_in[2];
  const float* W1  = (const float*)d_in[3];
  const float* b1  = (const float*)d_in[4];
  const float* W2  = (const float*)d_in[5];
  const float* b2  = (const float*)d_in[6];
  const float* Wc  = (const float*)d_in[7];
  const float* bc  = (const float*)d_in[8];

  float* out = (float*)d_out;   // [0,1280): rate ; then X
  float* P   = (float*)d_ws;    // [6400][800] fp32 = 20.48 MB

  gemm_kernel<<<GEMM_BLOCKS, BLK, 0, stream>>>(inp, W1, P);

  recur_kernel<<<BATCH + RPASTE, 64, 0, stream>>>(
      P, W2, b2, Wc, bc, b1, idx, out, inp, out + BATCH * NCLS);
}